// Round 6
// baseline (378.760 us; speedup 1.0000x reference)
//
#include <hip/hip_runtime.h>

typedef __attribute__((ext_vector_type(8))) __bf16 bf16x8;
typedef __attribute__((ext_vector_type(8))) unsigned short ushort8v;
typedef __attribute__((ext_vector_type(4))) float f32x4;
typedef __attribute__((ext_vector_type(4))) unsigned int u32x4;

__device__ __forceinline__ unsigned short f2bf(float f) {
  return __builtin_bit_cast(unsigned short, (__bf16)f);
}
__device__ __forceinline__ unsigned int pk2(float a, float b) {
  return (unsigned int)f2bf(a) | ((unsigned int)f2bf(b) << 16);
}

// Swizzled byte offsets (XOR row-bits into the 16B-slot index -> no bank conflicts, G4)
__device__ __forceinline__ int qoff(int row, int colb) {  // 256B rows (A/Q/K[64][128] bf16)
  return row * 256 + (colb ^ ((row & 7) << 4));
}
__device__ __forceinline__ int toff(int row, int colb) {  // 128B rows (S_raw[64][64] bf16)
  return row * 128 + (colb ^ ((row & 7) << 4));
}

// Barrier that does NOT drain vmcnt: LDS-ordering only (m201-verified pattern).
__device__ __forceinline__ void bar_lds() {
  asm volatile("s_waitcnt lgkmcnt(0)" ::: "memory");
  __builtin_amdgcn_s_barrier();
}

__global__ void prep_w(const float* __restrict__ Wq, const float* __restrict__ Wk,
                       const float* __restrict__ Wv, unsigned short* __restrict__ ws) {
  int i = blockIdx.x * 256 + threadIdx.x;
  if (i >= 3 * 16384) return;
  const float* s = (i < 16384) ? Wq : (i < 32768 ? Wk : Wv);
  ws[i] = f2bf(s[i & 16383]);
}

// LN-decouple correction vectors: cw[m][e][l] = ln_w_l . W_m[e][:],
// cb[m][e][l] = ln_b_l . W_m[e][:] + b_m[e].  (m: 0=Q,1=K,2=V; layout [m][e][l],
// l-contiguous so the GEMM1 epilogue reads float4 over rows.)
__global__ void prep_c(const float* __restrict__ Wq, const float* __restrict__ bq,
                       const float* __restrict__ Wk, const float* __restrict__ bk,
                       const float* __restrict__ Wv, const float* __restrict__ bv,
                       const float* __restrict__ lnw, const float* __restrict__ lnb,
                       float* __restrict__ cwcb) {
  int i = blockIdx.x * 256 + threadIdx.x;
  if (i >= 3 * 128 * 64) return;
  int m = i >> 13, e = (i >> 6) & 127, l = i & 63;
  const float* W = (m == 0) ? Wq : (m == 1 ? Wk : Wv);
  const float* b = (m == 0) ? bq : (m == 1 ? bk : bv);
  float sw = 0.f, sb = 0.f;
  for (int d = 0; d < 128; ++d) {
    float wv = W[e * 128 + d];
    sw += lnw[l * 128 + d] * wv;
    sb += lnb[l * 128 + d] * wv;
  }
  cwcb[i] = sw;
  cwcb[24576 + i] = sb + b[e];
}

// One row per block, grid 8192, 3 barriers. LayerNorm is decoupled from GEMM1:
// A = bf16(x .* ln_w) is packed to LDS WITHOUT mu/rstd (so pack + reduce-partials
// share ONE barrier), and the normalization is applied at the GEMM1 epilogue as
// y = rstd*(acc - mu*cw[l][e]) + cb[l][e] — the block-wide reduce latency hides
// under the MFMA phase instead of sitting at the head of the critical path.
// V stays in registers (r5's verified shuffle); S stored raw + deferred norm.
__global__ __launch_bounds__(512, 3) void fused_attn(
    const float* __restrict__ x, const unsigned short* __restrict__ wsW,
    const float* __restrict__ cwcb, const float* __restrict__ ln_w,
    float* __restrict__ out) {
  __shared__ __align__(16) unsigned char smem[49728];
  unsigned char* sA = smem;          // A[64][128] bf16 (qoff); S_raw[64][64] (toff) overlays after B2
  unsigned char* sQ = smem + 16384;  // Q[64][128] bf16 (qoff)
  unsigned char* sK = smem + 32768;  // K[64][128] bf16 (qoff)
  float* redS  = (float*)(smem + 49152);   // 16 floats LN scratch
  float* pPart = (float*)(smem + 49216);   // [8][16] S rowsum partials

  const int tid = threadIdx.x;
  const int lane = tid & 63;
  const int w = tid >> 6;            // wave 0..7
  const int l15 = lane & 15;
  const int l4 = lane >> 4;          // 0..3
  const size_t bofs = (size_t)blockIdx.x * 8192;

  const int col = (w << 4) + l15;    // this wave's Q/K/V output column
  const int row_x = tid >> 3;        // 0..63
  const int c0 = (tid & 7) << 4;     // 0..112

  // ---- Phase A: x load + ln_w load; reduce partials; pack A = bf16(x .* ln_w) ----
  float xv[16];
  {
    const float* xp = x + bofs + (size_t)row_x * 128 + c0;
#pragma unroll
    for (int i = 0; i < 4; ++i) {
      float4 a = *(const float4*)(xp + i * 4);
      xv[i*4+0]=a.x; xv[i*4+1]=a.y; xv[i*4+2]=a.z; xv[i*4+3]=a.w;
    }
  }
  float lw[16];
  {
    const float* pw = ln_w + row_x * 128 + c0;
#pragma unroll
    for (int i = 0; i < 4; ++i) {
      float4 a = *(const float4*)(pw + i * 4);
      lw[i*4+0]=a.x; lw[i*4+1]=a.y; lw[i*4+2]=a.z; lw[i*4+3]=a.w;
    }
  }
  float s1 = 0.f, s2 = 0.f;
#pragma unroll
  for (int i = 0; i < 16; ++i) { s1 += xv[i]; s2 += xv[i] * xv[i]; }
#pragma unroll
  for (int off = 32; off > 0; off >>= 1) {
    s1 += __shfl_xor(s1, off, 64);
    s2 += __shfl_xor(s2, off, 64);
  }
  if (lane == 0) { redS[w] = s1; redS[8 + w] = s2; }
  // pack A (no mu/rstd needed!)
#pragma unroll
  for (int h = 0; h < 2; ++h) {
    ushort8v t;
#pragma unroll
    for (int j = 0; j < 8; ++j)
      t[j] = f2bf(xv[h*8+j] * lw[h*8+j]);
    *(ushort8v*)(sA + qoff(row_x, (c0 << 1) + h * 16)) = t;
  }
  bar_lds();  // B1: A + reduce partials visible (single barrier for both)

  // mu/rstd: consumed only ~1 phase later at the GEMM1 epilogue — latency hidden
  float t1 = 0.f, t2 = 0.f;
#pragma unroll
  for (int p = 0; p < 8; ++p) { t1 += redS[p]; t2 += redS[8 + p]; }
  const float mu = t1 * (1.f / 8192.f);
  const float rstd = rsqrtf(t2 * (1.f / 8192.f) - mu * mu + 1e-5f);

  // ---- P1a: QK-pass (col-split): wave w -> Q,K cols [16w,16w+16) ----
  {
    bf16x8 wfq[4], wfk[4];
    const unsigned short* wpq = wsW + col * 128 + (l4 << 3);
    const unsigned short* wpk = wsW + 16384 + col * 128 + (l4 << 3);
#pragma unroll
    for (int kk = 0; kk < 4; ++kk) {
      wfq[kk] = *(const bf16x8*)(wpq + kk * 32);
      wfk[kk] = *(const bf16x8*)(wpk + kk * 32);
    }
#pragma unroll
    for (int mt = 0; mt < 4; ++mt) {
      const int i0m = mt * 16 + (l4 << 2);
      // correction vectors (L2-resident 192KB table; issued before MFMAs to overlap)
      f32x4 cwq = *(const f32x4*)(cwcb + col * 64 + i0m);
      f32x4 cbq = *(const f32x4*)(cwcb + 24576 + col * 64 + i0m);
      f32x4 cwk = *(const f32x4*)(cwcb + 8192 + col * 64 + i0m);
      f32x4 cbk = *(const f32x4*)(cwcb + 24576 + 8192 + col * 64 + i0m);
      bf16x8 aq[4];
#pragma unroll
      for (int kk = 0; kk < 4; ++kk)
        aq[kk] = *(const bf16x8*)(sA + qoff(mt * 16 + l15, kk * 64 + (l4 << 4)));
      f32x4 aQ = {0,0,0,0}, aK = {0,0,0,0};
#pragma unroll
      for (int kk = 0; kk < 4; ++kk) {
        aQ = __builtin_amdgcn_mfma_f32_16x16x32_bf16(aq[kk], wfq[kk], aQ, 0, 0, 0);
        aK = __builtin_amdgcn_mfma_f32_16x16x32_bf16(aq[kk], wfk[kk], aK, 0, 0, 0);
      }
#pragma unroll
      for (int rr = 0; rr < 4; ++rr) {
        float yq = rstd * (aQ[rr] - mu * cwq[rr]) + cbq[rr];
        yq = yq > 0.f ? yq + 1.f : __expf(yq);
        *(unsigned short*)(sQ + qoff(i0m + rr, col * 2)) = f2bf(yq);
        float yk = rstd * (aK[rr] - mu * cwk[rr]) + cbk[rr];
        yk = yk > 0.f ? yk + 1.f : __expf(yk);
        *(unsigned short*)(sK + qoff(i0m + rr, col * 2)) = f2bf(yk);
      }
    }
  }

  // ---- P1b: V-pass -> registers only (r5-verified shuffle). ----
  // C-layout source: lane(l4,l15) holds V[mt*16+l4*4+rr][16w+l15].
  // A-frag target:   lane(l4,l15) needs V[kf*32+l4*8+j][16w+l15], j=0..7.
  bf16x8 av[2];
  {
    bf16x8 wfv[4];
    const unsigned short* wpv = wsW + 2 * 16384 + col * 128 + (l4 << 3);
#pragma unroll
    for (int kk = 0; kk < 4; ++kk)
      wfv[kk] = *(const bf16x8*)(wpv + kk * 32);
    const int srcA = l15 + ((lane & 16) << 1);  // l15 + 32*(l4&1)
    const int srcB = srcA + 16;
    const bool hi = (l4 >> 1) != 0;             // l4>=2 -> use odd-mt data
#pragma unroll
    for (int kf = 0; kf < 2; ++kf) {
      const int i0a = (2 * kf) * 16 + (l4 << 2);
      const int i0b = i0a + 16;
      f32x4 cwv0 = *(const f32x4*)(cwcb + 2 * 8192 + col * 64 + i0a);
      f32x4 cbv0 = *(const f32x4*)(cwcb + 24576 + 2 * 8192 + col * 64 + i0a);
      f32x4 cwv1 = *(const f32x4*)(cwcb + 2 * 8192 + col * 64 + i0b);
      f32x4 cbv1 = *(const f32x4*)(cwcb + 24576 + 2 * 8192 + col * 64 + i0b);
      f32x4 aV0 = {0,0,0,0}, aV1 = {0,0,0,0};
#pragma unroll
      for (int kk = 0; kk < 4; ++kk) {
        bf16x8 aq0 = *(const bf16x8*)(sA + qoff((2*kf) * 16 + l15, kk * 64 + (l4 << 4)));
        aV0 = __builtin_amdgcn_mfma_f32_16x16x32_bf16(aq0, wfv[kk], aV0, 0, 0, 0);
      }
#pragma unroll
      for (int kk = 0; kk < 4; ++kk) {
        bf16x8 aq1 = *(const bf16x8*)(sA + qoff((2*kf+1) * 16 + l15, kk * 64 + (l4 << 4)));
        aV1 = __builtin_amdgcn_mfma_f32_16x16x32_bf16(aq1, wfv[kk], aV1, 0, 0, 0);
      }
      float y0[4], y1[4];
#pragma unroll
      for (int rr = 0; rr < 4; ++rr) {
        y0[rr] = rstd * (aV0[rr] - mu * cwv0[rr]) + cbv0[rr];
        y1[rr] = rstd * (aV1[rr] - mu * cwv1[rr]) + cbv1[rr];
      }
      unsigned pA0 = pk2(y0[0], y0[1]);
      unsigned pA1 = pk2(y0[2], y0[3]);
      unsigned pB0 = pk2(y1[0], y1[1]);
      unsigned pB1 = pk2(y1[2], y1[3]);
      unsigned d0a = __shfl((int)pA0, srcA, 64), d0b = __shfl((int)pB0, srcA, 64);
      unsigned d1a = __shfl((int)pA1, srcA, 64), d1b = __shfl((int)pB1, srcA, 64);
      unsigned d2a = __shfl((int)pA0, srcB, 64), d2b = __shfl((int)pB0, srcB, 64);
      unsigned d3a = __shfl((int)pA1, srcB, 64), d3b = __shfl((int)pB1, srcB, 64);
      u32x4 dd;
      dd[0] = hi ? d0b : d0a; dd[1] = hi ? d1b : d1a;
      dd[2] = hi ? d2b : d2a; dd[3] = hi ? d3b : d3a;
      av[kf] = __builtin_bit_cast(bf16x8, dd);
    }
  }
  bar_lds();  // B2: Q,K visible; all A reads done (A region dead)

  // ---- P2: S = Q K^T; wave (rt,h): rows [16rt,+16) x cols [32h,+32). RAW S out. ----
  const int rt = w >> 1;
  const int h = w & 1;
  const int i0s = rt * 16 + (l4 << 2);
  f32x4 xr[4];  // residual prefetch for P4
  {
    // residual x prefetch issued FIRST (vmcnt survives B3; lgkm-only barriers)
#pragma unroll
    for (int nt = 0; nt < 4; ++nt) {
      const int l = nt * 16 + l15;
      const int mb = (w << 4) + (l4 << 2);
      xr[nt] = *(const f32x4*)(x + bofs + (size_t)l * 128 + mb);
    }
    bf16x8 aq[4];
#pragma unroll
    for (int kk = 0; kk < 4; ++kk)
      aq[kk] = *(const bf16x8*)(sQ + qoff(rt * 16 + l15, kk * 64 + (l4 << 4)));
    f32x4 accS[2];
#pragma unroll
    for (int nt = 0; nt < 2; ++nt) {
      const int ntg = h * 2 + nt;
      f32x4 acc = {0,0,0,0};
#pragma unroll
      for (int kk = 0; kk < 4; ++kk) {
        bf16x8 bk_ = *(const bf16x8*)(sK + qoff(ntg * 16 + l15, kk * 64 + (l4 << 4)));
        acc = __builtin_amdgcn_mfma_f32_16x16x32_bf16(aq[kk], bk_, acc, 0, 0, 0);
      }
      accS[nt] = acc;
    }
    // partial rowsum over this half's 32 cols (reduce over l15)
    float p[4];
#pragma unroll
    for (int rr = 0; rr < 4; ++rr) p[rr] = accS[0][rr] + accS[1][rr];
#pragma unroll
    for (int off = 1; off < 16; off <<= 1) {
#pragma unroll
      for (int rr = 0; rr < 4; ++rr) p[rr] += __shfl_xor(p[rr], off, 64);
    }
    if (l15 == 0) {
#pragma unroll
      for (int rr = 0; rr < 4; ++rr)
        pPart[w * 16 + (l4 << 2) + rr] = p[rr];
    }
    // RAW S -> sA (toff); normalization deferred to post-P-MFMA
#pragma unroll
    for (int nt = 0; nt < 2; ++nt) {
      const int ntg = h * 2 + nt;
#pragma unroll
      for (int rr = 0; rr < 4; ++rr)
        *(unsigned short*)(sA + toff(i0s + rr, (ntg * 16 + l15) * 2)) = f2bf(accS[nt][rr]);
    }
  }
  bar_lds();  // B3: S_raw + pPart visible

  // ---- P4: P^T[m][l] = sum_i V[i][m] S[l][i]; scale by nv[l]; residual; store ----
  {
    float nv[4];
#pragma unroll
    for (int nt = 0; nt < 4; ++nt)
      nv[nt] = 1.f / (pPart[nt * 32 + l15] + pPart[nt * 32 + 16 + l15] + 1e-7f);
#pragma unroll
    for (int nt = 0; nt < 4; ++nt) {
      bf16x8 bs0 = *(const bf16x8*)(sA + toff(nt * 16 + l15, (l4 << 4)));
      bf16x8 bs1 = *(const bf16x8*)(sA + toff(nt * 16 + l15, 64 + (l4 << 4)));
      f32x4 acc = {0,0,0,0};
      acc = __builtin_amdgcn_mfma_f32_16x16x32_bf16(av[0], bs0, acc, 0, 0, 0);
      acc = __builtin_amdgcn_mfma_f32_16x16x32_bf16(av[1], bs1, acc, 0, 0, 0);
      const int l = nt * 16 + l15;
      const int mb = (w << 4) + (l4 << 2);
      const size_t idx = bofs + (size_t)l * 128 + mb;
      f32x4 o;
      o[0] = acc[0] * nv[nt] + xr[nt][0];
      o[1] = acc[1] * nv[nt] + xr[nt][1];
      o[2] = acc[2] * nv[nt] + xr[nt][2];
      o[3] = acc[3] * nv[nt] + xr[nt][3];
      *(f32x4*)(out + idx) = o;
    }
  }
}

extern "C" void kernel_launch(void* const* d_in, const int* in_sizes, int n_in,
                              void* d_out, int out_size, void* d_ws, size_t ws_size,
                              hipStream_t stream) {
  const float* x   = (const float*)d_in[0];
  const float* Wq  = (const float*)d_in[1];
  const float* bq  = (const float*)d_in[2];
  const float* Wk  = (const float*)d_in[3];
  const float* bk  = (const float*)d_in[4];
  const float* Wv  = (const float*)d_in[5];
  const float* bv  = (const float*)d_in[6];
  const float* lnw = (const float*)d_in[7];
  const float* lnb = (const float*)d_in[8];
  unsigned char* wsb = (unsigned char*)d_ws;
  unsigned short* wsW = (unsigned short*)wsb;        // 98304 B bf16 weights
  float* cwcb = (float*)(wsb + 98304);               // 196608 B correction vectors
  float* out = (float*)d_out;

  prep_w<<<192, 256, 0, stream>>>(Wq, Wk, Wv, wsW);
  prep_c<<<96, 256, 0, stream>>>(Wq, bq, Wk, bk, Wv, bv, lnw, lnb, cwcb);
  fused_attn<<<8192, 512, 0, stream>>>(x, wsW, cwcb, lnw, out);
}

// Round 7
// 291.697 us; speedup vs baseline: 1.2985x; 1.2985x over previous
//
#include <hip/hip_runtime.h>

typedef __attribute__((ext_vector_type(8))) __bf16 bf16x8;
typedef __attribute__((ext_vector_type(8))) unsigned short ushort8v;
typedef __attribute__((ext_vector_type(4))) float f32x4;
typedef __attribute__((ext_vector_type(4))) unsigned int u32x4;

__device__ __forceinline__ unsigned short f2bf(float f) {
  return __builtin_bit_cast(unsigned short, (__bf16)f);
}
__device__ __forceinline__ unsigned int pk2(float a, float b) {
  return (unsigned int)f2bf(a) | ((unsigned int)f2bf(b) << 16);
}

// Swizzled byte offsets (XOR row-bits into the 16B-slot index -> no bank conflicts, G4)
__device__ __forceinline__ int qoff(int row, int colb) {  // 256B rows (A/Q/K[64][128] bf16)
  return row * 256 + (colb ^ ((row & 7) << 4));
}
__device__ __forceinline__ int toff(int row, int colb) {  // 128B rows (S_raw[64][64] bf16)
  return row * 128 + (colb ^ ((row & 7) << 4));
}

// Barrier that does NOT drain vmcnt: LDS-ordering only (m201-verified pattern).
__device__ __forceinline__ void bar_lds() {
  asm volatile("s_waitcnt lgkmcnt(0)" ::: "memory");
  __builtin_amdgcn_s_barrier();
}

__global__ void prep_w(const float* __restrict__ Wq, const float* __restrict__ Wk,
                       const float* __restrict__ Wv, unsigned short* __restrict__ ws) {
  int i = blockIdx.x * 256 + threadIdx.x;
  if (i >= 3 * 16384) return;
  const float* s = (i < 16384) ? Wq : (i < 32768 ? Wk : Wv);
  ws[i] = f2bf(s[i & 16383]);
}

// LN-decouple correction tables in FRAGMENT ORDER (r6's gather fix):
// cwT[(m*4+mt)*512 + tid] = f32x4 over rr of  sum_d lnw[(i0m+rr)*128+d] * W_m[col*128+d]
// cbT[...]                = same with lnb, plus b_m[col].
// col/i0m derived from tid exactly as in fused_attn -> kernel loads are 16B/lane coalesced.
__global__ void prep_c(const float* __restrict__ Wq, const float* __restrict__ bq,
                       const float* __restrict__ Wk, const float* __restrict__ bk,
                       const float* __restrict__ Wv, const float* __restrict__ bv,
                       const float* __restrict__ lnw, const float* __restrict__ lnb,
                       float* __restrict__ cwcb) {
  int g = blockIdx.x * 256 + threadIdx.x;
  if (g >= 6144) return;
  int m = g >> 11;            // 0..2  (2048 entries per m)
  int mt = (g >> 9) & 3;      // 0..3
  int tid = g & 511;
  int w = tid >> 6, lane = tid & 63, l15 = lane & 15, l4 = lane >> 4;
  int col = (w << 4) | l15;
  int i0m = mt * 16 + (l4 << 2);
  const float* W = (m == 0) ? Wq : (m == 1 ? Wk : Wv);
  const float* b = (m == 0) ? bq : (m == 1 ? bk : bv);
  float sw[4] = {0.f, 0.f, 0.f, 0.f}, sb[4] = {0.f, 0.f, 0.f, 0.f};
  for (int d = 0; d < 128; ++d) {
    float wv = W[col * 128 + d];
#pragma unroll
    for (int rr = 0; rr < 4; ++rr) {
      sw[rr] += lnw[(i0m + rr) * 128 + d] * wv;
      sb[rr] += lnb[(i0m + rr) * 128 + d] * wv;
    }
  }
  float bb = b[col];
  float4* cwT = (float4*)cwcb;
  float4* cbT = (float4*)(cwcb + 24576);
  cwT[g] = make_float4(sw[0], sw[1], sw[2], sw[3]);
  cbT[g] = make_float4(sb[0] + bb, sb[1] + bb, sb[2] + bb, sb[3] + bb);
}

// 4 rows/block (grid 2048), software-pipelined, 3 lgkm-only barriers/row.
// LN decoupled: A = bf16(x .* ln_w) packs BEFORE the reduce barrier; mu/rstd applied
// at the GEMM1 epilogue via coalesced fragment-order correction tables.
// V stays in registers (r5/r6-verified shuffle). S_raw gets its OWN LDS region so the
// row loop needs no trailing barrier (hazard-audited: every cross-row reuse is
// separated by >=1 lgkmcnt(0)+barrier between last read and next write).
__global__ __launch_bounds__(512, 2) void fused_attn(
    const float* __restrict__ x, const unsigned short* __restrict__ wsW,
    const float* __restrict__ cwcb, const float* __restrict__ ln_w,
    float* __restrict__ out) {
  __shared__ __align__(16) unsigned char smem[57920];
  unsigned char* sA = smem;          // A[64][128] bf16 (qoff)
  unsigned char* sQ = smem + 16384;  // Q[64][128] bf16 (qoff)
  unsigned char* sK = smem + 32768;  // K[64][128] bf16 (qoff)
  unsigned char* sS = smem + 49152;  // S_raw[64][64] bf16 (toff)
  float* redS  = (float*)(smem + 57344);   // 16 floats LN scratch
  float* pPart = (float*)(smem + 57408);   // [8][16] S rowsum partials

  const int tid = threadIdx.x;
  const int lane = tid & 63;
  const int w = tid >> 6;            // wave 0..7
  const int l15 = lane & 15;
  const int l4 = lane >> 4;          // 0..3
  const size_t base = (size_t)blockIdx.x * (4 * 8192);

  const int col = (w << 4) + l15;    // this wave's Q/K/V output column
  const int row_x = tid >> 3;        // 0..63
  const int c0 = (tid & 7) << 4;     // 0..112

  const f32x4* cwT = (const f32x4*)cwcb;
  const f32x4* cbT = (const f32x4*)(cwcb + 24576);

  // ---- persistent: Q,K weights (32 VGPR) + ln_w slice (16 VGPR), once per block ----
  bf16x8 wfq[4], wfk[4];
  {
    const unsigned short* wpq = wsW + col * 128 + (l4 << 3);
    const unsigned short* wpk = wsW + 16384 + col * 128 + (l4 << 3);
#pragma unroll
    for (int kk = 0; kk < 4; ++kk) {
      wfq[kk] = *(const bf16x8*)(wpq + kk * 32);
      wfk[kk] = *(const bf16x8*)(wpk + kk * 32);
    }
  }
  float lw[16];
  {
    const float* pw = ln_w + row_x * 128 + c0;
#pragma unroll
    for (int i = 0; i < 4; ++i) {
      float4 a = *(const float4*)(pw + i * 4);
      lw[i*4+0]=a.x; lw[i*4+1]=a.y; lw[i*4+2]=a.z; lw[i*4+3]=a.w;
    }
  }

  // ---- prologue: row 0's x slice ----
  float xv[16];
  {
    const float* xp = x + base + (size_t)row_x * 128 + c0;
#pragma unroll
    for (int i = 0; i < 4; ++i) {
      float4 a = *(const float4*)(xp + i * 4);
      xv[i*4+0]=a.x; xv[i*4+1]=a.y; xv[i*4+2]=a.z; xv[i*4+3]=a.w;
    }
  }

#pragma unroll 1
  for (int r = 0; r < 4; ++r) {
    const size_t bofs = base + (size_t)r * 8192;

    // ---- Phase A: reduce partials + pack A = bf16(x .* ln_w)  (no mu/rstd needed) ----
    float s1 = 0.f, s2 = 0.f;
#pragma unroll
    for (int i = 0; i < 16; ++i) { s1 += xv[i]; s2 += xv[i] * xv[i]; }
#pragma unroll
    for (int off = 32; off > 0; off >>= 1) {
      s1 += __shfl_xor(s1, off, 64);
      s2 += __shfl_xor(s2, off, 64);
    }
    if (lane == 0) { redS[w] = s1; redS[8 + w] = s2; }
#pragma unroll
    for (int h = 0; h < 2; ++h) {
      ushort8v t;
#pragma unroll
      for (int j = 0; j < 8; ++j)
        t[j] = f2bf(xv[h*8+j] * lw[h*8+j]);
      *(ushort8v*)(sA + qoff(row_x, (c0 << 1) + h * 16)) = t;
    }
    // refill xv with next row's x NOW — in flight across the whole GEMM chain
    if (r < 3) {
      const float* xp = x + bofs + 8192 + (size_t)row_x * 128 + c0;
#pragma unroll
      for (int i = 0; i < 4; ++i) {
        float4 a = *(const float4*)(xp + i * 4);
        xv[i*4+0]=a.x; xv[i*4+1]=a.y; xv[i*4+2]=a.z; xv[i*4+3]=a.w;
      }
    }
    bar_lds();  // B1: A + reduce partials visible

    // mu/rstd: consumed only at the GEMM1 epilogue — reduce latency hidden under MFMAs
    float t1 = 0.f, t2 = 0.f;
#pragma unroll
    for (int p = 0; p < 8; ++p) { t1 += redS[p]; t2 += redS[8 + p]; }
    const float mu = t1 * (1.f / 8192.f);
    const float rstd = rsqrtf(t2 * (1.f / 8192.f) - mu * mu + 1e-5f);

    // ---- P1a: QK-pass; corrections via coalesced fragment-order table ----
#pragma unroll
    for (int mt = 0; mt < 4; ++mt) {
      const int i0m = mt * 16 + (l4 << 2);
      f32x4 cwq = cwT[mt * 512 + tid];
      f32x4 cbq = cbT[mt * 512 + tid];
      f32x4 cwk = cwT[(4 + mt) * 512 + tid];
      f32x4 cbk = cbT[(4 + mt) * 512 + tid];
      bf16x8 aq[4];
#pragma unroll
      for (int kk = 0; kk < 4; ++kk)
        aq[kk] = *(const bf16x8*)(sA + qoff(mt * 16 + l15, kk * 64 + (l4 << 4)));
      f32x4 aQ = {0,0,0,0}, aK = {0,0,0,0};
#pragma unroll
      for (int kk = 0; kk < 4; ++kk) {
        aQ = __builtin_amdgcn_mfma_f32_16x16x32_bf16(aq[kk], wfq[kk], aQ, 0, 0, 0);
        aK = __builtin_amdgcn_mfma_f32_16x16x32_bf16(aq[kk], wfk[kk], aK, 0, 0, 0);
      }
#pragma unroll
      for (int rr = 0; rr < 4; ++rr) {
        float yq = rstd * (aQ[rr] - mu * cwq[rr]) + cbq[rr];
        yq = yq > 0.f ? yq + 1.f : __expf(yq);
        *(unsigned short*)(sQ + qoff(i0m + rr, col * 2)) = f2bf(yq);
        float yk = rstd * (aK[rr] - mu * cwk[rr]) + cbk[rr];
        yk = yk > 0.f ? yk + 1.f : __expf(yk);
        *(unsigned short*)(sK + qoff(i0m + rr, col * 2)) = f2bf(yk);
      }
    }

    // ---- P1b: V-pass -> registers only (r5/r6-verified shuffle) ----
    bf16x8 av[2];
    {
      bf16x8 wfv[4];
      const unsigned short* wpv = wsW + 2 * 16384 + col * 128 + (l4 << 3);
#pragma unroll
      for (int kk = 0; kk < 4; ++kk)
        wfv[kk] = *(const bf16x8*)(wpv + kk * 32);
      const int srcA = l15 + ((lane & 16) << 1);  // l15 + 32*(l4&1)
      const int srcB = srcA + 16;
      const bool hi = (l4 >> 1) != 0;
#pragma unroll
      for (int kf = 0; kf < 2; ++kf) {
        f32x4 cwv0 = cwT[(8 + 2 * kf) * 512 + tid];
        f32x4 cbv0 = cbT[(8 + 2 * kf) * 512 + tid];
        f32x4 cwv1 = cwT[(8 + 2 * kf + 1) * 512 + tid];
        f32x4 cbv1 = cbT[(8 + 2 * kf + 1) * 512 + tid];
        f32x4 aV0 = {0,0,0,0}, aV1 = {0,0,0,0};
#pragma unroll
        for (int kk = 0; kk < 4; ++kk) {
          bf16x8 aq0 = *(const bf16x8*)(sA + qoff((2*kf) * 16 + l15, kk * 64 + (l4 << 4)));
          aV0 = __builtin_amdgcn_mfma_f32_16x16x32_bf16(aq0, wfv[kk], aV0, 0, 0, 0);
        }
#pragma unroll
        for (int kk = 0; kk < 4; ++kk) {
          bf16x8 aq1 = *(const bf16x8*)(sA + qoff((2*kf+1) * 16 + l15, kk * 64 + (l4 << 4)));
          aV1 = __builtin_amdgcn_mfma_f32_16x16x32_bf16(aq1, wfv[kk], aV1, 0, 0, 0);
        }
        float y0[4], y1[4];
#pragma unroll
        for (int rr = 0; rr < 4; ++rr) {
          y0[rr] = rstd * (aV0[rr] - mu * cwv0[rr]) + cbv0[rr];
          y1[rr] = rstd * (aV1[rr] - mu * cwv1[rr]) + cbv1[rr];
        }
        unsigned pA0 = pk2(y0[0], y0[1]);
        unsigned pA1 = pk2(y0[2], y0[3]);
        unsigned pB0 = pk2(y1[0], y1[1]);
        unsigned pB1 = pk2(y1[2], y1[3]);
        unsigned d0a = __shfl((int)pA0, srcA, 64), d0b = __shfl((int)pB0, srcA, 64);
        unsigned d1a = __shfl((int)pA1, srcA, 64), d1b = __shfl((int)pB1, srcA, 64);
        unsigned d2a = __shfl((int)pA0, srcB, 64), d2b = __shfl((int)pB0, srcB, 64);
        unsigned d3a = __shfl((int)pA1, srcB, 64), d3b = __shfl((int)pB1, srcB, 64);
        u32x4 dd;
        dd[0] = hi ? d0b : d0a; dd[1] = hi ? d1b : d1a;
        dd[2] = hi ? d2b : d2a; dd[3] = hi ? d3b : d3a;
        av[kf] = __builtin_bit_cast(bf16x8, dd);
      }
    }
    bar_lds();  // B2: Q,K visible; all sA reads done

    // ---- P2: S = Q K^T; wave (rt,h): rows [16rt,+16) x cols [32h,+32). RAW S out. ----
    const int rt = w >> 1;
    const int h = w & 1;
    const int i0s = rt * 16 + (l4 << 2);
    f32x4 xr[4];
    {
      bf16x8 aq[4];
#pragma unroll
      for (int kk = 0; kk < 4; ++kk)
        aq[kk] = *(const bf16x8*)(sQ + qoff(rt * 16 + l15, kk * 64 + (l4 << 4)));
      f32x4 accS[2];
#pragma unroll
      for (int nt = 0; nt < 2; ++nt) {
        const int ntg = h * 2 + nt;
        f32x4 acc = {0,0,0,0};
#pragma unroll
        for (int kk = 0; kk < 4; ++kk) {
          bf16x8 bk_ = *(const bf16x8*)(sK + qoff(ntg * 16 + l15, kk * 64 + (l4 << 4)));
          acc = __builtin_amdgcn_mfma_f32_16x16x32_bf16(aq[kk], bk_, acc, 0, 0, 0);
        }
        accS[nt] = acc;
      }
      // residual prefetch (issued here; consumed in P4 — flight covers rowsum+B3)
#pragma unroll
      for (int nt = 0; nt < 4; ++nt) {
        const int l = nt * 16 + l15;
        const int mb = (w << 4) + (l4 << 2);
        xr[nt] = *(const f32x4*)(x + bofs + (size_t)l * 128 + mb);
      }
      // partial rowsum over this half's 32 cols
      float p[4];
#pragma unroll
      for (int rr = 0; rr < 4; ++rr) p[rr] = accS[0][rr] + accS[1][rr];
#pragma unroll
      for (int off = 1; off < 16; off <<= 1) {
#pragma unroll
        for (int rr = 0; rr < 4; ++rr) p[rr] += __shfl_xor(p[rr], off, 64);
      }
      if (l15 == 0) {
#pragma unroll
        for (int rr = 0; rr < 4; ++rr)
          pPart[w * 16 + (l4 << 2) + rr] = p[rr];
      }
      // RAW S -> sS (toff); normalization deferred to post-P-MFMA
#pragma unroll
      for (int nt = 0; nt < 2; ++nt) {
        const int ntg = h * 2 + nt;
#pragma unroll
        for (int rr = 0; rr < 4; ++rr)
          *(unsigned short*)(sS + toff(i0s + rr, (ntg * 16 + l15) * 2)) = f2bf(accS[nt][rr]);
      }
    }
    bar_lds();  // B3: S_raw + pPart visible

    // ---- P4: P^T[m][l] = sum_i V[i][m] S[l][i]; scale by nv[l]; residual; store ----
    {
      float nv[4];
#pragma unroll
      for (int nt = 0; nt < 4; ++nt)
        nv[nt] = 1.f / (pPart[nt * 32 + l15] + pPart[nt * 32 + 16 + l15] + 1e-7f);
#pragma unroll
      for (int nt = 0; nt < 4; ++nt) {
        bf16x8 bs0 = *(const bf16x8*)(sS + toff(nt * 16 + l15, (l4 << 4)));
        bf16x8 bs1 = *(const bf16x8*)(sS + toff(nt * 16 + l15, 64 + (l4 << 4)));
        f32x4 acc = {0,0,0,0};
        acc = __builtin_amdgcn_mfma_f32_16x16x32_bf16(av[0], bs0, acc, 0, 0, 0);
        acc = __builtin_amdgcn_mfma_f32_16x16x32_bf16(av[1], bs1, acc, 0, 0, 0);
        const int l = nt * 16 + l15;
        const int mb = (w << 4) + (l4 << 2);
        const size_t idx = bofs + (size_t)l * 128 + mb;
        f32x4 o;
        o[0] = acc[0] * nv[nt] + xr[nt][0];
        o[1] = acc[1] * nv[nt] + xr[nt][1];
        o[2] = acc[2] * nv[nt] + xr[nt][2];
        o[3] = acc[3] * nv[nt] + xr[nt][3];
        *(f32x4*)(out + idx) = o;
      }
    }
    // no trailing barrier: row r+1's pre-B1 LDS writes touch only sA/redS, which
    // have no post-B3 readers in row r (sS/pPart are separate regions).
  }
}

extern "C" void kernel_launch(void* const* d_in, const int* in_sizes, int n_in,
                              void* d_out, int out_size, void* d_ws, size_t ws_size,
                              hipStream_t stream) {
  const float* x   = (const float*)d_in[0];
  const float* Wq  = (const float*)d_in[1];
  const float* bq  = (const float*)d_in[2];
  const float* Wk  = (const float*)d_in[3];
  const float* bk  = (const float*)d_in[4];
  const float* Wv  = (const float*)d_in[5];
  const float* bv  = (const float*)d_in[6];
  const float* lnw = (const float*)d_in[7];
  const float* lnb = (const float*)d_in[8];
  unsigned char* wsb = (unsigned char*)d_ws;
  unsigned short* wsW = (unsigned short*)wsb;        // 98304 B bf16 weights
  float* cwcb = (float*)(wsb + 98304);               // 196608 B correction tables
  float* out = (float*)d_out;

  prep_w<<<192, 256, 0, stream>>>(Wq, Wk, Wv, wsW);
  prep_c<<<24, 256, 0, stream>>>(Wq, bq, Wk, bk, Wv, bv, lnw, lnb, cwcb);
  fused_attn<<<2048, 512, 0, stream>>>(x, wsW, cwcb, lnw, out);
}

// Round 8
// 211.180 us; speedup vs baseline: 1.7935x; 1.3813x over previous
//
#include <hip/hip_runtime.h>

typedef __attribute__((ext_vector_type(8))) __bf16 bf16x8;
typedef __attribute__((ext_vector_type(8))) unsigned short ushort8v;
typedef __attribute__((ext_vector_type(4))) float f32x4;

__device__ __forceinline__ unsigned short f2bf(float f) {
  return __builtin_bit_cast(unsigned short, (__bf16)f);
}

// Swizzled byte offsets (XOR row-bits into the 16B-slot index -> no bank conflicts, G4)
__device__ __forceinline__ int qoff(int row, int colb) {  // 256B rows (A/Q/K[64][128] bf16)
  return row * 256 + (colb ^ ((row & 7) << 4));
}
__device__ __forceinline__ int toff(int row, int colb) {  // 128B rows (VT[128][64], S[64][64] bf16)
  return row * 128 + (colb ^ ((row & 7) << 4));
}

// Barrier that does NOT drain vmcnt: LDS-ordering only (m201-verified pattern).
__device__ __forceinline__ void bar_lds() {
  asm volatile("s_waitcnt lgkmcnt(0)" ::: "memory");
  __builtin_amdgcn_s_barrier();
}

__global__ void prep_w(const float* __restrict__ Wq, const float* __restrict__ Wk,
                       const float* __restrict__ Wv, unsigned short* __restrict__ ws) {
  int i = blockIdx.x * 256 + threadIdx.x;
  if (i >= 3 * 16384) return;
  const float* s = (i < 16384) ? Wq : (i < 32768 ? Wk : Wv);
  ws[i] = f2bf(s[i & 16383]);
}

// 4 rows/block (grid 2048), 3 lgkm-only barriers/row.  r3-champion structure plus:
// (1) LN stats pipelined one row ahead: row r+1's s1/s2 shfl-reduce runs inside row
//     r's S-phase (covered by S MFMAs), double-buffered redS -> the reduce chain and
//     its barrier vanish from the row head (prologue pays it once for row 0).
// (2) Raw S + deferred normalization (r5-verified): nv applied post-P-MFMA; kills
//     the normalize pass + its barrier.  sS is a separate region so the row loop
//     needs no trailing barrier (each barrier's lgkmcnt(0) drains readers first).
__global__ __launch_bounds__(512, 2) void fused_attn(
    const float* __restrict__ x, const unsigned short* __restrict__ wsW,
    const float* __restrict__ bq, const float* __restrict__ bk, const float* __restrict__ bv,
    const float* __restrict__ ln_w, const float* __restrict__ ln_b,
    float* __restrict__ out) {
  __shared__ __align__(16) unsigned char smem[74368];
  unsigned char* sA  = smem;            // A[64][128] bf16 (qoff)
  unsigned char* sQ  = smem + 16384;    // Q[64][128] bf16 (qoff)
  unsigned char* sK  = smem + 32768;    // K[64][128] bf16 (qoff)
  unsigned char* sVT = smem + 49152;    // V^T[128][64] bf16 (toff)
  unsigned char* sS  = smem + 65536;    // S_raw[64][64] bf16 (toff)
  float* redS  = (float*)(smem + 73728);   // [2][16] double-buffered LN partials
  float* pPart = (float*)(smem + 73856);   // [8][16] S rowsum partials

  const int tid = threadIdx.x;
  const int lane = tid & 63;
  const int w = tid >> 6;            // wave 0..7
  const int l15 = lane & 15;
  const int l4 = lane >> 4;          // 0..3
  const size_t base = (size_t)blockIdx.x * (4 * 8192);

  // ---- persistent: weights (24 VGPR) + biases + ln slices (32 VGPR) ----
  bf16x8 wf[3][4];
  const int col = (w << 4) + l15;
#pragma unroll
  for (int m = 0; m < 3; ++m) {
    const unsigned short* wp = wsW + m * 16384 + col * 128 + (l4 << 3);
#pragma unroll
    for (int kk = 0; kk < 4; ++kk)
      wf[m][kk] = *(const bf16x8*)(wp + kk * 32);
  }
  const float biasQ = bq[col], biasK = bk[col], biasV = bv[col];

  const int row_x = tid >> 3;        // 0..63
  const int c0 = (tid & 7) << 4;     // 0..112
  float lw[16], lb[16];
  {
    const float* pw = ln_w + row_x * 128 + c0;
    const float* pb = ln_b + row_x * 128 + c0;
#pragma unroll
    for (int i = 0; i < 4; ++i) {
      float4 a = *(const float4*)(pw + i * 4);
      lw[i*4+0]=a.x; lw[i*4+1]=a.y; lw[i*4+2]=a.z; lw[i*4+3]=a.w;
      float4 b = *(const float4*)(pb + i * 4);
      lb[i*4+0]=b.x; lb[i*4+1]=b.y; lb[i*4+2]=b.z; lb[i*4+3]=b.w;
    }
  }

  // ---- prologue: row 0's x + its LN reduce (paid once) ----
  float xv[16];
  {
    const float* xp = x + base + (size_t)row_x * 128 + c0;
#pragma unroll
    for (int i = 0; i < 4; ++i) {
      float4 a = *(const float4*)(xp + i * 4);
      xv[i*4+0]=a.x; xv[i*4+1]=a.y; xv[i*4+2]=a.z; xv[i*4+3]=a.w;
    }
  }
  {
    float s1 = 0.f, s2 = 0.f;
#pragma unroll
    for (int i = 0; i < 16; ++i) { s1 += xv[i]; s2 += xv[i] * xv[i]; }
#pragma unroll
    for (int off = 32; off > 0; off >>= 1) {
      s1 += __shfl_xor(s1, off, 64);
      s2 += __shfl_xor(s2, off, 64);
    }
    if (lane == 0) { redS[w] = s1; redS[8 + w] = s2; }
  }
  bar_lds();  // prologue: redS buf0 visible

#pragma unroll 1
  for (int r = 0; r < 4; ++r) {
    const size_t bofs = base + (size_t)r * 8192;

    // ---- head: stats ready immediately (pipelined); pack A; issue next-row x ----
    const float* rb = redS + (r & 1) * 16;
    float t1 = 0.f, t2 = 0.f;
#pragma unroll
    for (int p = 0; p < 8; ++p) { t1 += rb[p]; t2 += rb[8 + p]; }
    const float mu = t1 * (1.f / 8192.f);
    const float rstd = rsqrtf(t2 * (1.f / 8192.f) - mu * mu + 1e-5f);
#pragma unroll
    for (int h = 0; h < 2; ++h) {
      ushort8v t;
#pragma unroll
      for (int j = 0; j < 8; ++j)
        t[j] = f2bf((xv[h*8+j] - mu) * rstd * lw[h*8+j] + lb[h*8+j]);
      *(ushort8v*)(sA + qoff(row_x, (c0 << 1) + h * 16)) = t;
    }
    if (r < 3) {  // refill xv: in flight across GEMM1; reduced during P2
      const float* xp = x + bofs + 8192 + (size_t)row_x * 128 + c0;
#pragma unroll
      for (int i = 0; i < 4; ++i) {
        float4 a = *(const float4*)(xp + i * 4);
        xv[i*4+0]=a.x; xv[i*4+1]=a.y; xv[i*4+2]=a.z; xv[i*4+3]=a.w;
      }
    }
    bar_lds();  // B_A: A visible

    // ---- P1: GEMM1 (col-split): Q,K,V from reg-weights (r3 verbatim) ----
#pragma unroll
    for (int mt = 0; mt < 4; ++mt) {
      bf16x8 aq[4];
#pragma unroll
      for (int kk = 0; kk < 4; ++kk)
        aq[kk] = *(const bf16x8*)(sA + qoff(mt * 16 + l15, kk * 64 + (l4 << 4)));
      const int i0m = mt * 16 + (l4 << 2);
      f32x4 aQ = {0,0,0,0}, aK = {0,0,0,0}, aV = {0,0,0,0};
#pragma unroll
      for (int kk = 0; kk < 4; ++kk) {
        aQ = __builtin_amdgcn_mfma_f32_16x16x32_bf16(aq[kk], wf[0][kk], aQ, 0, 0, 0);
        aK = __builtin_amdgcn_mfma_f32_16x16x32_bf16(aq[kk], wf[1][kk], aK, 0, 0, 0);
        aV = __builtin_amdgcn_mfma_f32_16x16x32_bf16(aq[kk], wf[2][kk], aV, 0, 0, 0);
      }
#pragma unroll
      for (int rr = 0; rr < 4; ++rr) {
        float zq = aQ[rr] + biasQ; zq = zq > 0.f ? zq + 1.f : __expf(zq);
        *(unsigned short*)(sQ + qoff(i0m + rr, col * 2)) = f2bf(zq);
        float zk = aK[rr] + biasK; zk = zk > 0.f ? zk + 1.f : __expf(zk);
        *(unsigned short*)(sK + qoff(i0m + rr, col * 2)) = f2bf(zk);
      }
      ushort4 pk;
      pk.x = f2bf(aV[0] + biasV); pk.y = f2bf(aV[1] + biasV);
      pk.z = f2bf(aV[2] + biasV); pk.w = f2bf(aV[3] + biasV);
      *(ushort4*)(sVT + toff(col, i0m * 2)) = pk;
    }
    bar_lds();  // B_QK: Q,K,VT visible; A dead

    // ---- P2: S = Q K^T (wave (rt,h)); rowsum partials; NEXT row's LN reduce; raw S ----
    const int rt = w >> 1;
    const int h = w & 1;
    const int i0s = rt * 16 + (l4 << 2);
    f32x4 xr[4];
    {
      bf16x8 aq[4];
#pragma unroll
      for (int kk = 0; kk < 4; ++kk)
        aq[kk] = *(const bf16x8*)(sQ + qoff(rt * 16 + l15, kk * 64 + (l4 << 4)));
      // residual prefetch (consumed in P4; flight covers the rest of P2 + B_S)
#pragma unroll
      for (int nt = 0; nt < 4; ++nt) {
        const int l = nt * 16 + l15;
        const int mb = (w << 4) + (l4 << 2);
        xr[nt] = *(const f32x4*)(x + bofs + (size_t)l * 128 + mb);
      }
      f32x4 accS[2];
#pragma unroll
      for (int nt = 0; nt < 2; ++nt) {
        const int ntg = h * 2 + nt;
        f32x4 acc = {0,0,0,0};
#pragma unroll
        for (int kk = 0; kk < 4; ++kk) {
          bf16x8 bk_ = *(const bf16x8*)(sK + qoff(ntg * 16 + l15, kk * 64 + (l4 << 4)));
          acc = __builtin_amdgcn_mfma_f32_16x16x32_bf16(aq[kk], bk_, acc, 0, 0, 0);
        }
        accS[nt] = acc;
      }
      // partial rowsum over this half's 32 cols (4-step shfl over l15)
      float p[4];
#pragma unroll
      for (int rr = 0; rr < 4; ++rr) p[rr] = accS[0][rr] + accS[1][rr];
#pragma unroll
      for (int off = 1; off < 16; off <<= 1) {
#pragma unroll
        for (int rr = 0; rr < 4; ++rr) p[rr] += __shfl_xor(p[rr], off, 64);
      }
      if (l15 == 0) {
#pragma unroll
        for (int rr = 0; rr < 4; ++rr)
          pPart[w * 16 + (l4 << 2) + rr] = p[rr];
      }
      // NEXT row's LN reduce (xv already refilled at head; S-MFMAs cover the chain)
      if (r < 3) {
        float n1 = 0.f, n2 = 0.f;
#pragma unroll
        for (int i = 0; i < 16; ++i) { n1 += xv[i]; n2 += xv[i] * xv[i]; }
#pragma unroll
        for (int off = 32; off > 0; off >>= 1) {
          n1 += __shfl_xor(n1, off, 64);
          n2 += __shfl_xor(n2, off, 64);
        }
        if (lane == 0) {
          float* nb = redS + ((r + 1) & 1) * 16;
          nb[w] = n1; nb[8 + w] = n2;
        }
      }
      // RAW S -> sS (toff); normalization deferred to P4
#pragma unroll
      for (int nt = 0; nt < 2; ++nt) {
        const int ntg = h * 2 + nt;
#pragma unroll
        for (int rr = 0; rr < 4; ++rr)
          *(unsigned short*)(sS + toff(i0s + rr, (ntg * 16 + l15) * 2)) = f2bf(accS[nt][rr]);
      }
    }
    bar_lds();  // B_S: S_raw + pPart (+ next redS) visible

    // ---- P4: P^T[m][l] = sum_i VT[m][i] S[l][i]; scale by nv[l]; residual; store ----
    {
      float nv[4];
#pragma unroll
      for (int nt = 0; nt < 4; ++nt)
        nv[nt] = 1.f / (pPart[nt * 32 + l15] + pPart[nt * 32 + 16 + l15] + 1e-7f);
      bf16x8 av[2];
#pragma unroll
      for (int kk = 0; kk < 2; ++kk)
        av[kk] = *(const bf16x8*)(sVT + toff((w << 4) + l15, kk * 64 + (l4 << 4)));
#pragma unroll
      for (int nt = 0; nt < 4; ++nt) {
        bf16x8 bs0 = *(const bf16x8*)(sS + toff(nt * 16 + l15, (l4 << 4)));
        bf16x8 bs1 = *(const bf16x8*)(sS + toff(nt * 16 + l15, 64 + (l4 << 4)));
        f32x4 acc = {0,0,0,0};
        acc = __builtin_amdgcn_mfma_f32_16x16x32_bf16(av[0], bs0, acc, 0, 0, 0);
        acc = __builtin_amdgcn_mfma_f32_16x16x32_bf16(av[1], bs1, acc, 0, 0, 0);
        const int l = nt * 16 + l15;
        const int mb = (w << 4) + (l4 << 2);
        const size_t idx = bofs + (size_t)l * 128 + mb;
        f32x4 o;
        o[0] = acc[0] * nv[nt] + xr[nt][0];
        o[1] = acc[1] * nv[nt] + xr[nt][1];
        o[2] = acc[2] * nv[nt] + xr[nt][2];
        o[3] = acc[3] * nv[nt] + xr[nt][3];
        *(f32x4*)(out + idx) = o;
      }
    }
    // no trailing barrier: next row's pre-B_A LDS writes (sA, none else) have their
    // last readers (GEMM1, row r) separated by B_QK+B_S; B_A's lgkmcnt(0) drains
    // each wave's P4 reads (sS/sVT/pPart) before any row r+1 write can occur.
  }
}

extern "C" void kernel_launch(void* const* d_in, const int* in_sizes, int n_in,
                              void* d_out, int out_size, void* d_ws, size_t ws_size,
                              hipStream_t stream) {
  const float* x   = (const float*)d_in[0];
  const float* Wq  = (const float*)d_in[1];
  const float* bq  = (const float*)d_in[2];
  const float* Wk  = (const float*)d_in[3];
  const float* bk  = (const float*)d_in[4];
  const float* Wv  = (const float*)d_in[5];
  const float* bv  = (const float*)d_in[6];
  const float* lnw = (const float*)d_in[7];
  const float* lnb = (const float*)d_in[8];
  unsigned short* ws = (unsigned short*)d_ws;  // 96 KB bf16 weights
  float* out = (float*)d_out;

  prep_w<<<192, 256, 0, stream>>>(Wq, Wk, Wv, ws);
  fused_attn<<<2048, 512, 0, stream>>>(x, ws, bq, bk, bv, lnw, lnb, out);
}